// Round 7
// baseline (304.819 us; speedup 1.0000x reference)
//
#include <hip/hip_runtime.h>
#include <hip/hip_bf16.h>
#include <math.h>

#define B_   4
#define CIN  64
#define P_   1728
#define N_   1729
#define C_   256
#define NH_  8
#define HD_  32
#define M_   (B_*N_)   // 6916 rows
#define NPAD 1792      // 28 * 64
#define STB  (2*M_)    // 13832 floats per stats buffer

typedef __bf16 bf16x8 __attribute__((ext_vector_type(8)));
typedef __bf16 bf16x4 __attribute__((ext_vector_type(4)));
typedef float  f32x4  __attribute__((ext_vector_type(4)));
typedef float  f32x16 __attribute__((ext_vector_type(16)));

// ---------------------------------------------------------------------------
// lnprep: cw[n] = sum_k g[k]*W[k][n], bw[n] = sum_k b[k]*W[k][n] for the two
// LN-folded GEMMs (qkv: 768 cols, fc1: 256 cols) per layer.
// lnc layout per layer (stride 2048): [0,768)cwq [768,1536)bwq
// [1536,1792)cw1 [1792,2048)bw1.
// ---------------------------------------------------------------------------
__global__ __launch_bounds__(256) void lnprep(
    const float* __restrict__ Wqkv, const float* __restrict__ W1,
    const float* __restrict__ ln1_g, const float* __restrict__ ln1_b,
    const float* __restrict__ ln2_g, const float* __restrict__ ln2_b,
    float* __restrict__ lnc)
{
    int gid = blockIdx.x*256 + threadIdx.x;      // [0, 2048)
    if (gid >= 2048) return;
    int l = gid >> 10, n = gid & 1023;
    float cw = 0.f, bw = 0.f;
    if (n < 768) {
        const float* W = Wqkv + (size_t)l*C_*768;
        const float* g = ln1_g + l*C_;
        const float* b = ln1_b + l*C_;
        for (int k = 0; k < C_; ++k) {
            float w = W[(size_t)k*768 + n];
            cw += g[k]*w; bw += b[k]*w;
        }
        lnc[l*2048 + n]       = cw;
        lnc[l*2048 + 768 + n] = bw;
    } else {
        int nn = n - 768;
        const float* W = W1 + (size_t)l*C_*C_;
        const float* g = ln2_g + l*C_;
        const float* b = ln2_b + l*C_;
        for (int k = 0; k < C_; ++k) {
            float w = W[(size_t)k*C_ + nn];
            cw += g[k]*w; bw += b[k]*w;
        }
        lnc[l*2048 + 1536 + nn] = cw;
        lnc[l*2048 + 1792 + nn] = bw;
    }
}

// ---------------------------------------------------------------------------
// wprep3: weights -> bf16 W^T[n][k]; Wqkv scaled by ln1_g[k], W1 by ln2_g[k]
// (LN gain folded into weights; LN mean/bias handled in consumer epilogues).
// ---------------------------------------------------------------------------
__global__ __launch_bounds__(256) void wprep3(
    const float* __restrict__ Wqkv, const float* __restrict__ Wproj,
    const float* __restrict__ W1,   const float* __restrict__ W2,
    const float* __restrict__ ln1_g, const float* __restrict__ ln2_g,
    __bf16* __restrict__ wT)
{
    int z = blockIdx.z, which = z >> 1, layer = z & 1;
    const float* src; __bf16* dst; int NC;
    if (which == 0) {
        src = Wqkv + (size_t)layer*C_*768;
        dst = wT   + (size_t)layer*768*256;
        NC  = 768;
    } else {
        NC = 256;
        const float* b3 = (which == 1) ? Wproj : (which == 2) ? W1 : W2;
        src = b3 + (size_t)layer*65536;
        dst = wT + 2*768*256 + (size_t)((which-1)*2 + layer)*65536;
    }
    int n0 = blockIdx.x*32; if (n0 >= NC) return;
    int k0 = blockIdx.y*32;
    __shared__ float tile[32][33];
    int c = threadIdx.x & 31, r = threadIdx.x >> 5;
    for (int rr = r; rr < 32; rr += 8)
        tile[rr][c] = src[(size_t)(k0+rr)*NC + n0 + c];
    __syncthreads();
    float gs = 1.f;                     // dst[n][k0+c] = W[k0+c][n] * g[k0+c]
    if (which == 0) gs = ln1_g[layer*C_ + k0 + c];
    else if (which == 2) gs = ln2_g[layer*C_ + k0 + c];
    for (int rr = r; rr < 32; rr += 8)
        dst[(size_t)(n0+rr)*256 + k0 + c] = (__bf16)(tile[c][rr] * gs);
}

// ---------------------------------------------------------------------------
// embed4: one block per row. Writes t fp32 + tbf bf16 + row stats (buf0,
// direct -- block owns the whole row). Extra blocks: kB/vB pad zeroing and
// zeroing of stats buffers 1..4 (used via atomics later).
// ---------------------------------------------------------------------------
__global__ __launch_bounds__(256) void embed4(
    const float* __restrict__ x, const float* __restrict__ Wpe,
    const float* __restrict__ bpe, const float* __restrict__ cls,
    float* __restrict__ t, __bf16* __restrict__ tbf,
    __bf16* __restrict__ kB, __bf16* __restrict__ vB,
    float* __restrict__ stats)
{
    __shared__ float rs[8];
    if (blockIdx.x >= M_) {
        int ex = blockIdx.x - M_;
        if (ex < 252) {               // padzero: keys n in [N_, NPAD)
            int idx = ex*256 + threadIdx.x;
            if (idx < 32*63*32) {
                int d  = idx & 31;
                int n  = (idx >> 5) % 63 + N_;
                int bh = idx / (63*32);
                kB[((size_t)bh*NPAD + n)*32 + d] = (__bf16)0.f;
                vB[((size_t)bh*32 + d)*NPAD + n] = (__bf16)0.f;
            }
        } else {                      // zero stats buffers 1..4
            int si = (ex - 252)*256 + threadIdx.x;
            if (si < 4*STB) stats[STB + si] = 0.f;
        }
        return;
    }
    int row = blockIdx.x;
    int b = row / N_, n = row - b*N_;
    int c = threadIdx.x;
    float val;
    if (n == 0) val = cls[c];
    else {
        int p = n - 1;
        val = bpe[c];
        for (int ci = 0; ci < CIN; ++ci)
            val += x[(size_t)(b*CIN + ci)*P_ + p] * Wpe[ci*C_ + c];
    }
    t[(size_t)row*C_ + c]   = val;
    tbf[(size_t)row*C_ + c] = (__bf16)val;

    float s1 = val, s2 = val*val;
    #pragma unroll
    for (int off = 32; off >= 1; off >>= 1) {
        s1 += __shfl_xor(s1, off);
        s2 += __shfl_xor(s2, off);
    }
    int wvi = c >> 6;
    if ((c & 63) == 0) { rs[wvi] = s1; rs[wvi+4] = s2; }
    __syncthreads();
    if (c == 0) {
        stats[2*(size_t)row]     = rs[0]+rs[1]+rs[2]+rs[3];
        stats[2*(size_t)row + 1] = rs[4]+rs[5]+rs[6]+rs[7];
    }
}

// ---------------------------------------------------------------------------
// gemm6: gemm4 core (unchanged hot loop), NC=256. Epilogue options:
//  LNFIX: A was RAW t (bf16) against g-scaled weights; apply
//         val = rstd*(acc - mean*cw[col]) + bw[col] using precomputed stats.
//  STATS: accumulate row sum/sumsq of updated t into statso (atomics).
//  TBF:   also write bf16 copy of updated t.
// ---------------------------------------------------------------------------
template<bool GELU, bool BIAS, bool OUTBF, bool ADD, bool STATS, bool LNFIX, bool TBF>
__global__ __launch_bounds__(256) void gemm6(
    const __bf16* __restrict__ A, const __bf16* __restrict__ Wt,
    const float* __restrict__ bias, float* __restrict__ outF,
    __bf16* __restrict__ outB, __bf16* __restrict__ tbfo,
    float* __restrict__ statso, const float* __restrict__ statsi,
    const float* __restrict__ cw, const float* __restrict__ bw)
{
    __shared__ __align__(16) __bf16 As[2][64*64];
    __shared__ __align__(16) __bf16 Bs[2][64*64];
    int r0 = blockIdx.x*64, c0 = blockIdx.y*64;
    int tid = threadIdx.x;
    int wv = tid >> 6, lane = tid & 63, quad = lane >> 4, mn = lane & 15;
    int sr = tid >> 2, sc = tid & 3;
    int ga = r0 + sr; if (ga >= M_) ga = M_ - 1;

    f32x4 acc[4];
    #pragma unroll
    for (int ct = 0; ct < 4; ++ct)
        #pragma unroll
        for (int rr = 0; rr < 4; ++rr) acc[ct][rr] = 0.f;

    bf16x8 ra0, ra1, rb0, rb1;
#define GLOAD(KC) do {                                                   \
        ra0 = *(const bf16x8*)&A[(size_t)ga*256 + (KC)*64 + sc*8];       \
        ra1 = *(const bf16x8*)&A[(size_t)ga*256 + (KC)*64 + sc*8 + 32];  \
        rb0 = *(const bf16x8*)&Wt[(size_t)(c0+sr)*256 + (KC)*64 + sc*8]; \
        rb1 = *(const bf16x8*)&Wt[(size_t)(c0+sr)*256 + (KC)*64 + sc*8 + 32]; \
    } while (0)
#define SSTORE(BUF) do {                                                 \
        *(bf16x8*)&As[BUF][sr*64 + ((sc ^ (sr & 7))*8)]       = ra0;     \
        *(bf16x8*)&As[BUF][sr*64 + (((sc+4) ^ (sr & 7))*8)]   = ra1;     \
        *(bf16x8*)&Bs[BUF][sr*64 + ((sc ^ (sr & 7))*8)]       = rb0;     \
        *(bf16x8*)&Bs[BUF][sr*64 + (((sc+4) ^ (sr & 7))*8)]   = rb1;     \
    } while (0)

    GLOAD(0);
    SSTORE(0);
    __syncthreads();

    for (int kc = 0; kc < 4; ++kc) {
        int cur = kc & 1;
        if (kc < 3) GLOAD(kc+1);
        __builtin_amdgcn_sched_barrier(0);

        #pragma unroll
        for (int h = 0; h < 2; ++h) {
            bf16x8 a = *(const bf16x8*)&As[cur][(wv*16 + mn)*64 + (((h*4+quad) ^ (mn & 7))*8)];
            #pragma unroll
            for (int ct = 0; ct < 4; ++ct) {
                bf16x8 b = *(const bf16x8*)&Bs[cur][(ct*16 + mn)*64 + (((h*4+quad) ^ (mn & 7))*8)];
                acc[ct] = __builtin_amdgcn_mfma_f32_16x16x32_bf16(a, b, acc[ct], 0, 0, 0);
            }
        }

        if (kc < 3) {
            SSTORE(cur^1);
            __syncthreads();
        }
    }
#undef GLOAD
#undef SSTORE

    float mean4[4], rstd4[4];
    if (LNFIX) {
        #pragma unroll
        for (int rr = 0; rr < 4; ++rr) {
            int row = r0 + wv*16 + quad*4 + rr; if (row >= M_) row = M_-1;
            float s1 = statsi[2*row], s2 = statsi[2*row+1];
            float mn_ = s1*(1.0f/C_);
            mean4[rr] = mn_;
            rstd4[rr] = rsqrtf(fmaxf(s2*(1.0f/C_) - mn_*mn_, 0.0f) + 1e-5f);
        }
    }
    float rs1[4] = {0.f,0.f,0.f,0.f}, rs2[4] = {0.f,0.f,0.f,0.f};
    #pragma unroll
    for (int ct = 0; ct < 4; ++ct) {
        int col = c0 + ct*16 + mn;
        float cwv = 0.f, bwv = 0.f;
        if (LNFIX) { cwv = cw[col]; bwv = bw[col]; }
        #pragma unroll
        for (int rr = 0; rr < 4; ++rr) {
            int row = r0 + wv*16 + quad*4 + rr;
            if (row >= M_) continue;
            float val = acc[ct][rr];
            if (LNFIX) val = rstd4[rr]*(val - mean4[rr]*cwv) + bwv;
            if (BIAS) val += bias[col];
            if (GELU) val = 0.5f*val*(1.f + erff(val*0.70710678118654752f));
            size_t oi = (size_t)row*C_ + col;
            if (OUTBF) outB[oi] = (__bf16)val;
            else if (ADD) {
                float tv = outF[oi] + val;
                outF[oi] = tv;
                if (TBF) tbfo[oi] = (__bf16)tv;
                if (STATS) { rs1[rr] += tv; rs2[rr] += tv*tv; }
            }
            else outF[oi] = val;
        }
    }
    if (STATS) {
        #pragma unroll
        for (int rr = 0; rr < 4; ++rr) {
            float s1 = rs1[rr], s2 = rs2[rr];
            s1 += __shfl_xor(s1, 1); s1 += __shfl_xor(s1, 2);
            s1 += __shfl_xor(s1, 4); s1 += __shfl_xor(s1, 8);
            s2 += __shfl_xor(s2, 1); s2 += __shfl_xor(s2, 2);
            s2 += __shfl_xor(s2, 4); s2 += __shfl_xor(s2, 8);
            int row = r0 + wv*16 + quad*4 + rr;
            if (mn == 0 && row < M_) {
                atomicAdd(&statso[2*row],     s1);
                atomicAdd(&statso[2*row + 1], s2);
            }
        }
    }
}

// ---------------------------------------------------------------------------
// gemm_qkv6: unchanged core on RAW tbf vs g-scaled Wqkv; epilogue applies the
// LN fixup then packs qB (scaled by log2e/sqrt(hd)), kB, vB^T.
// ---------------------------------------------------------------------------
__global__ __launch_bounds__(256) void gemm_qkv6(
    const __bf16* __restrict__ A, const __bf16* __restrict__ Wt,
    const float* __restrict__ statsi, const float* __restrict__ lncl,
    __bf16* __restrict__ qB, __bf16* __restrict__ kB, __bf16* __restrict__ vB)
{
    __shared__ __align__(16) __bf16 As[2][64*64];
    __shared__ __align__(16) __bf16 Bs[2][64*64];
    int r0 = blockIdx.x*64, c0 = blockIdx.y*64;
    int tid = threadIdx.x;
    int wv = tid >> 6, lane = tid & 63, quad = lane >> 4, mn = lane & 15;
    int sr = tid >> 2, sc = tid & 3;
    int ga = r0 + sr; if (ga >= M_) ga = M_ - 1;

    f32x4 acc[4];
    #pragma unroll
    for (int ct = 0; ct < 4; ++ct)
        #pragma unroll
        for (int rr = 0; rr < 4; ++rr) acc[ct][rr] = 0.f;

    bf16x8 ra0, ra1, rb0, rb1;
#define GLOAD(KC) do {                                                   \
        ra0 = *(const bf16x8*)&A[(size_t)ga*256 + (KC)*64 + sc*8];       \
        ra1 = *(const bf16x8*)&A[(size_t)ga*256 + (KC)*64 + sc*8 + 32];  \
        rb0 = *(const bf16x8*)&Wt[(size_t)(c0+sr)*256 + (KC)*64 + sc*8]; \
        rb1 = *(const bf16x8*)&Wt[(size_t)(c0+sr)*256 + (KC)*64 + sc*8 + 32]; \
    } while (0)
#define SSTORE(BUF) do {                                                 \
        *(bf16x8*)&As[BUF][sr*64 + ((sc ^ (sr & 7))*8)]       = ra0;     \
        *(bf16x8*)&As[BUF][sr*64 + (((sc+4) ^ (sr & 7))*8)]   = ra1;     \
        *(bf16x8*)&Bs[BUF][sr*64 + ((sc ^ (sr & 7))*8)]       = rb0;     \
        *(bf16x8*)&Bs[BUF][sr*64 + (((sc+4) ^ (sr & 7))*8)]   = rb1;     \
    } while (0)

    GLOAD(0);
    SSTORE(0);
    __syncthreads();

    for (int kc = 0; kc < 4; ++kc) {
        int cur = kc & 1;
        if (kc < 3) GLOAD(kc+1);
        __builtin_amdgcn_sched_barrier(0);

        #pragma unroll
        for (int h = 0; h < 2; ++h) {
            bf16x8 a = *(const bf16x8*)&As[cur][(wv*16 + mn)*64 + (((h*4+quad) ^ (mn & 7))*8)];
            #pragma unroll
            for (int ct = 0; ct < 4; ++ct) {
                bf16x8 b = *(const bf16x8*)&Bs[cur][(ct*16 + mn)*64 + (((h*4+quad) ^ (mn & 7))*8)];
                acc[ct] = __builtin_amdgcn_mfma_f32_16x16x32_bf16(a, b, acc[ct], 0, 0, 0);
            }
        }

        if (kc < 3) {
            SSTORE(cur^1);
            __syncthreads();
        }
    }
#undef GLOAD
#undef SSTORE

    float mean4[4], rstd4[4];
    #pragma unroll
    for (int rr = 0; rr < 4; ++rr) {
        int row = r0 + wv*16 + quad*4 + rr; if (row >= M_) row = M_-1;
        float s1 = statsi[2*row], s2 = statsi[2*row+1];
        float mn_ = s1*(1.0f/C_);
        mean4[rr] = mn_;
        rstd4[rr] = rsqrtf(fmaxf(s2*(1.0f/C_) - mn_*mn_, 0.0f) + 1e-5f);
    }

    const float qsc = 0.2550348727f;   // log2(e)/sqrt(32)
    #pragma unroll
    for (int ct = 0; ct < 4; ++ct) {
        int col = c0 + ct*16 + mn;
        float cwv = lncl[col], bwv = lncl[768 + col];
        #pragma unroll
        for (int rr = 0; rr < 4; ++rr) {
            int row = r0 + wv*16 + quad*4 + rr;
            if (row >= M_) continue;
            int b = row / N_, n = row - b*N_;
            float val = rstd4[rr]*(acc[ct][rr] - mean4[rr]*cwv) + bwv;
            if (col < 256) {
                int h = col >> 5, dd = col & 31;
                qB[((size_t)(b*NH_+h)*NPAD + n)*32 + dd] = (__bf16)(val*qsc);
            } else if (col < 512) {
                int h = (col-256) >> 5, dd = col & 31;
                kB[((size_t)(b*NH_+h)*NPAD + n)*32 + dd] = (__bf16)val;
            } else {
                int h = (col-512) >> 5, dd = col & 31;
                vB[((size_t)(b*NH_+h)*32 + dd)*NPAD + n] = (__bf16)val;
            }
        }
    }
}

// ---------------------------------------------------------------------------
// attn13 (frozen): converged ~42 us across 5 structural variants.
// ---------------------------------------------------------------------------
#define LKS 40     // lk row stride (bf16): 32 data + 8 pad
#define LVS 136    // lvt row stride (bf16): 128 data + 8 pad

__device__ __forceinline__ float fexp2(float x) {
    float r; asm("v_exp_f32 %0, %1" : "=v"(r) : "v"(x)); return r;
}
__device__ __forceinline__ unsigned cvtpk_bf16(float lo, float hi) {
    unsigned r;
    asm("v_cvt_pk_bf16_f32 %0, %1, %2" : "=v"(r) : "v"(lo), "v"(hi));
    return r;
}

__global__ __launch_bounds__(128) void attn13(
    const __bf16* __restrict__ qB, const __bf16* __restrict__ kB,
    const __bf16* __restrict__ vB, __bf16* __restrict__ o)
{
    int bh = blockIdx.x, b = bh >> 3, h = bh & 7;
    int q0 = blockIdx.y * 64;
    int tid = threadIdx.x;
    int wv = tid >> 6, lane = tid & 63, lo5 = lane & 31, hi = lane >> 5;

    __shared__ __align__(16) __bf16 lk[2][128*LKS];   // 2 x 10240 B
    __shared__ __align__(16) __bf16 lvt[2][32*LVS];   // 2 x  8704 B

    const __bf16* kbase = kB + (size_t)bh*NPAD*32;
    const __bf16* vbase = vB + (size_t)bh*32*NPAD;

    const __bf16* qrow = qB + ((size_t)bh*NPAD + q0 + wv*32 + lo5)*32 + hi*8;
    bf16x8 qf0 = *(const bf16x8*)(qrow);        // d = hi*8 .. +7
    bf16x8 qf1 = *(const bf16x8*)(qrow + 16);   // d = 16+hi*8 .. +7

    f32x16 oaccA, oaccB;
    #pragma unroll
    for (int r = 0; r < 16; ++r) { oaccA[r] = 0.f; oaccB[r] = 0.f; }
    float lsum = 0.f;

    int vr = tid >> 2, vc = tid & 3;            // V staging: row, 64B chunk

    bf16x8 ks0, ks1, ks2, ks3, vs0, vs1, vs2, vs3;
#define ATTN_LOAD(T) do {                                              \
        const __bf16* kp_ = kbase + ((size_t)((T)*128 + tid))*32;      \
        ks0 = *(const bf16x8*)(kp_);                                   \
        ks1 = *(const bf16x8*)(kp_ + 8);                               \
        ks2 = *(const bf16x8*)(kp_ + 16);                              \
        ks3 = *(const bf16x8*)(kp_ + 24);                              \
        const __bf16* vp_ = vbase + (size_t)vr*NPAD + (T)*128 + vc*32; \
        vs0 = *(const bf16x8*)(vp_);                                   \
        vs1 = *(const bf16x8*)(vp_ + 8);                               \
        vs2 = *(const bf16x8*)(vp_ + 16);                              \
        vs3 = *(const bf16x8*)(vp_ + 24);                              \
    } while (0)
#define ATTN_STORE(BUF) do {                                           \
        __bf16* kd = &lk[BUF][tid*LKS];                                \
        *(bf16x8*)(kd)      = ks0;  *(bf16x8*)(kd + 8)  = ks1;         \
        *(bf16x8*)(kd + 16) = ks2;  *(bf16x8*)(kd + 24) = ks3;         \
        __bf16* vd = &lvt[BUF][vr*LVS + vc*32];                        \
        *(bf16x8*)(vd)      = vs0;  *(bf16x8*)(vd + 8)  = vs1;         \
        *(bf16x8*)(vd + 16) = vs2;  *(bf16x8*)(vd + 24) = vs3;         \
    } while (0)

    ATTN_LOAD(0);
    ATTN_STORE(0);
    __syncthreads();

    for (int t = 0; t < 14; ++t) {
        int cur = t & 1;
        if (t < 13) ATTN_LOAD(t+1);
        __builtin_amdgcn_sched_barrier(0);

        f32x16 s[4];
        __builtin_amdgcn_s_setprio(1);
        #pragma unroll
        for (int kg = 0; kg < 4; ++kg) {
            const __bf16* kf = &lk[cur][(kg*32 + lo5)*LKS + hi*8];
            bf16x8 kf0 = *(const bf16x8*)(kf);
            bf16x8 kf1 = *(const bf16x8*)(kf + 16);
            #pragma unroll
            for (int r = 0; r < 16; ++r) s[kg][r] = 0.f;
            s[kg] = __builtin_amdgcn_mfma_f32_32x32x16_bf16(kf0, qf0, s[kg], 0, 0, 0);
            s[kg] = __builtin_amdgcn_mfma_f32_32x32x16_bf16(kf1, qf1, s[kg], 0, 0, 0);
        }
        __builtin_amdgcn_s_setprio(0);

        #pragma unroll
        for (int kg = 0; kg < 4; ++kg) {
            float p[16];
            #pragma unroll
            for (int r = 0; r < 16; ++r) p[r] = fexp2(s[kg][r]);
            float l0 = 0.f, l1 = 0.f;
            #pragma unroll
            for (int r = 0; r < 8; ++r) { l0 += p[r]; l1 += p[r+8]; }
            lsum += l0 + l1;

            unsigned a0 = cvtpk_bf16(p[0],  p[1]),  a1 = cvtpk_bf16(p[2],  p[3]);
            unsigned b0 = cvtpk_bf16(p[4],  p[5]),  b1 = cvtpk_bf16(p[6],  p[7]);
            unsigned c0 = cvtpk_bf16(p[8],  p[9]),  c1 = cvtpk_bf16(p[10], p[11]);
            unsigned d0 = cvtpk_bf16(p[12], p[13]), d1 = cvtpk_bf16(p[14], p[15]);
            asm("v_permlane32_swap_b32 %0, %1" : "+v"(a0), "+v"(b0));
            asm("v_permlane32_swap_b32 %0, %1" : "+v"(a1), "+v"(b1));
            asm("v_permlane32_swap_b32 %0, %1" : "+v"(c0), "+v"(d0));
            asm("v_permlane32_swap_b32 %0, %1" : "+v"(c1), "+v"(d1));
            union { bf16x8 v; unsigned u[4]; } f0, f1;
            f0.u[0] = a0; f0.u[1] = a1; f0.u[2] = b0; f0.u[3] = b1;
            f1.u[0] = c0; f1.u[1] = c1; f1.u[2] = d0; f1.u[3] = d1;

            const __bf16* vf = &lvt[cur][lo5*LVS + kg*32 + hi*8];
            bf16x8 vf0 = *(const bf16x8*)(vf);
            bf16x8 vf1 = *(const bf16x8*)(vf + 16);
            __builtin_amdgcn_s_setprio(1);
            if (kg & 1) {
                oaccB = __builtin_amdgcn_mfma_f32_32x32x16_bf16(f0.v, vf0, oaccB, 0, 0, 0);
                oaccB = __builtin_amdgcn_mfma_f32_32x32x16_bf16(f1.v, vf1, oaccB, 0, 0, 0);
            } else {
                oaccA = __builtin_amdgcn_mfma_f32_32x32x16_bf16(f0.v, vf0, oaccA, 0, 0, 0);
                oaccA = __builtin_amdgcn_mfma_f32_32x32x16_bf16(f1.v, vf1, oaccA, 0, 0, 0);
            }
            __builtin_amdgcn_s_setprio(0);
        }

        if (t < 13) {
            ATTN_STORE(cur^1);
            __syncthreads();
        }
    }
#undef ATTN_LOAD
#undef ATTN_STORE

    lsum += __shfl_xor(lsum, 32);
    float inv = 1.0f / (lsum - 63.0f);

    #pragma unroll
    for (int r = 0; r < 16; ++r) {
        float oa = oaccA[r] + oaccB[r];
        int qrw = (r & 3) + 8*(r >> 2) + 4*hi;
        float li = __shfl(inv, qrw);
        int q = q0 + wv*32 + qrw;
        if (q < N_)
            o[((size_t)b*N_ + q)*C_ + h*HD_ + lo5] = (__bf16)(oa * li);
    }
}

// ---------------------------------------------------------------------------
// featln: fused final-LayerNorm + feature transpose + cls extraction.
// ---------------------------------------------------------------------------
__global__ __launch_bounds__(256) void featln(
    const float* __restrict__ t, const float* __restrict__ stats,
    const float* __restrict__ g, const float* __restrict__ bb,
    float* __restrict__ out_cls, float* __restrict__ out_feat)
{
    int bx = blockIdx.x;
    if (bx == 54) {
        if (blockIdx.y != 0) return;
        int b = blockIdx.z, c = threadIdx.x;
        size_t row = (size_t)b*N_;
        float s1 = stats[2*row], s2 = stats[2*row+1];
        float mean = s1*(1.0f/C_);
        float rstd = rsqrtf(fmaxf(s2*(1.0f/C_) - mean*mean, 0.0f) + 1e-5f);
        out_cls[b*C_ + c] = (t[row*C_ + c] - mean)*rstd*g[c] + bb[c];
        return;
    }
    __shared__ float tl[32][33];
    int p0 = bx*32, c0 = blockIdx.y*32, b = blockIdx.z;
    int cc = threadIdx.x & 31, rr = threadIdx.x >> 5;
    float gg = g[c0+cc], bv = bb[c0+cc];
    for (int i = rr; i < 32; i += 8) {
        size_t row = (size_t)b*N_ + 1 + p0 + i;
        float s1 = stats[2*row], s2 = stats[2*row+1];
        float mean = s1*(1.0f/C_);
        float rstd = rsqrtf(fmaxf(s2*(1.0f/C_) - mean*mean, 0.0f) + 1e-5f);
        tl[i][cc] = (t[row*C_ + c0 + cc] - mean)*rstd*gg + bv;
    }
    __syncthreads();
    for (int i = rr; i < 32; i += 8)
        out_feat[((size_t)(b*C_) + c0 + i)*P_ + p0 + cc] = tl[cc][i];
}

// ---------------------------------------------------------------------------
extern "C" void kernel_launch(void* const* d_in, const int* in_sizes, int n_in,
                              void* d_out, int out_size, void* d_ws, size_t ws_size,
                              hipStream_t stream)
{
    const float* x        = (const float*)d_in[0];
    const float* W_pe     = (const float*)d_in[1];
    const float* b_pe     = (const float*)d_in[2];
    const float* cls_tok  = (const float*)d_in[3];
    const float* ln1_g    = (const float*)d_in[4];
    const float* ln1_b    = (const float*)d_in[5];
    const float* Wqkv     = (const float*)d_in[6];
    const float* Wproj    = (const float*)d_in[7];
    const float* bproj    = (const float*)d_in[8];
    const float* ln2_g    = (const float*)d_in[9];
    const float* ln2_b    = (const float*)d_in[10];
    const float* W1       = (const float*)d_in[11];
    const float* b1       = (const float*)d_in[12];
    const float* W2       = (const float*)d_in[13];
    const float* b2       = (const float*)d_in[14];
    const float* normf_g  = (const float*)d_in[15];
    const float* normf_b  = (const float*)d_in[16];

    const size_t MC = (size_t)M_*C_;    // 1,770,496
    float*  ws    = (float*)d_ws;
    float*  t     = ws;                              // MC fp32
    float*  stats = ws + MC;                         // 5 bufs x STB floats
    float*  lnc   = stats + 5*STB + 88;              // 4096 floats (aligned-ish)
    __bf16* tbf   = (__bf16*)(lnc + 4096);           // MC bf16
    __bf16* hbf   = tbf + MC;                        // MC bf16
    __bf16* obf   = hbf + MC;                        // MC bf16
    __bf16* wT    = obf + MC;                        // 786432 bf16
    __bf16* qB    = wT + 2*768*256 + 6*256*256;      // [32][NPAD][32]
    __bf16* kB    = qB + (size_t)B_*NH_*NPAD*32;
    __bf16* vB    = kB + (size_t)B_*NH_*NPAD*32;     // [32][32][NPAD]

    __bf16* projT = wT + 2*768*256;
    __bf16* w1T   = projT + 2*256*256;
    __bf16* w2T   = w1T   + 2*256*256;

    float* out_cls  = (float*)d_out;
    float* out_feat = out_cls + B_*C_;

    wprep3<<<dim3(24, 8, 8), 256, 0, stream>>>(
        Wqkv, Wproj, W1, W2, ln1_g, ln2_g, wT);
    lnprep<<<8, 256, 0, stream>>>(Wqkv, W1, ln1_g, ln1_b, ln2_g, ln2_b, lnc);
    embed4<<<M_ + 252 + 217, 256, 0, stream>>>(
        x, W_pe, b_pe, cls_tok, t, tbf, kB, vB, stats);

    const int GRID_M = (M_ + 63) / 64;   // 109
    for (int i = 0; i < 2; ++i) {
        gemm_qkv6<<<dim3(GRID_M, 12), 256, 0, stream>>>(
            tbf, wT + (size_t)i*768*256,
            stats + (i ? 2 : 0)*STB, lnc + i*2048, qB, kB, vB);
        attn13<<<dim3(32, 28), 128, 0, stream>>>(qB, kB, vB, obf);
        // proj: t += o@Wproj + bproj; emit tbf + ln2 stats
        gemm6<false,true,false,true,true,false,true><<<dim3(GRID_M, 4), 256, 0, stream>>>(
            obf, projT + (size_t)i*65536, bproj + i*C_, t, nullptr, tbf,
            stats + (i ? 3 : 1)*STB, nullptr, nullptr, nullptr);
        // fc1: h = gelu(LN2(t)@W1' + bw1 + b1) from RAW tbf
        gemm6<true,true,true,false,false,true,false><<<dim3(GRID_M, 4), 256, 0, stream>>>(
            tbf, w1T + (size_t)i*65536, b1 + i*C_, nullptr, hbf, nullptr,
            nullptr, stats + (i ? 3 : 1)*STB,
            lnc + i*2048 + 1536, lnc + i*2048 + 1792);
        // fc2: t += h@W2 + b2; emit tbf + next-LN (or final) stats
        gemm6<false,true,false,true,true,false,true><<<dim3(GRID_M, 4), 256, 0, stream>>>(
            hbf, w2T + (size_t)i*65536, b2 + i*C_, t, nullptr, tbf,
            stats + (i ? 4 : 2)*STB, nullptr, nullptr, nullptr);
    }

    featln<<<dim3(55, 8, 4), 256, 0, stream>>>(
        t, stats + 4*STB, normf_g, normf_b, out_cls, out_feat);
}

// Round 8
// 277.554 us; speedup vs baseline: 1.0982x; 1.0982x over previous
//
#include <hip/hip_runtime.h>
#include <hip/hip_bf16.h>
#include <math.h>

#define B_   4
#define CIN  64
#define P_   1728
#define N_   1729
#define C_   256
#define NH_  8
#define HD_  32
#define M_   (B_*N_)   // 6916 rows
#define NPAD 1792      // 28 * 64
#define NB_EMBED 6916  // (B_*N_*C_)/256

typedef __bf16 bf16x8 __attribute__((ext_vector_type(8)));
typedef __bf16 bf16x4 __attribute__((ext_vector_type(4)));
typedef float  f32x4  __attribute__((ext_vector_type(4)));
typedef float  f32x16 __attribute__((ext_vector_type(16)));

// ---------------------------------------------------------------------------
// embed3: patch embed + (extra blocks) kB/vB pad zeroing + stats zeroing.
// ---------------------------------------------------------------------------
__global__ __launch_bounds__(256) void embed3(
    const float* __restrict__ x, const float* __restrict__ Wpe,
    const float* __restrict__ bpe, const float* __restrict__ cls,
    float* __restrict__ t, __bf16* __restrict__ kB, __bf16* __restrict__ vB,
    float* __restrict__ stats)
{
    if (blockIdx.x >= NB_EMBED) {
        int ex = blockIdx.x - NB_EMBED;
        if (ex < 252) {               // padzero: keys n in [N_, NPAD)
            int idx = ex*256 + threadIdx.x;
            if (idx < 32*63*32) {
                int d  = idx & 31;
                int n  = (idx >> 5) % 63 + N_;
                int bh = idx / (63*32);
                kB[((size_t)bh*NPAD + n)*32 + d] = (__bf16)0.f;
                vB[((size_t)bh*32 + d)*NPAD + n] = (__bf16)0.f;
            }
        } else {                      // zero final-LN stats accumulator
            int si = (ex - 252)*256 + threadIdx.x;
            if (si < 2*M_) stats[si] = 0.f;
        }
        return;
    }
    int idx = blockIdx.x*256 + threadIdx.x;        // [0, B*N*C)
    int c   = idx & 255;
    int n   = (idx >> 8) % N_;
    int b   = idx / (N_*256);
    if (n == 0) { t[idx] = cls[c]; return; }
    int p = n - 1;
    float acc = bpe[c];
    for (int ci = 0; ci < CIN; ++ci)
        acc += x[(size_t)(b*CIN + ci)*P_ + p] * Wpe[ci*C_ + c];
    t[idx] = acc;
}

// ---------------------------------------------------------------------------
// ln4: LayerNorm, 4 rows/block (one wave each), float4 in, bf16x4 out.
// Standalone LN measured cheaper than fusing into GEMM (R5: +28us, R7: +22us).
// ---------------------------------------------------------------------------
__global__ __launch_bounds__(256) void ln4(
    const float* __restrict__ in, __bf16* __restrict__ out,
    const float* __restrict__ g, const float* __restrict__ bb)
{
    int wv = threadIdx.x >> 6, lane = threadIdx.x & 63;
    size_t row = (size_t)blockIdx.x*4 + wv;
    float4 v = *(const float4*)&in[row*C_ + lane*4];
    float s1 = (v.x+v.y)+(v.z+v.w);
    float s2 = (v.x*v.x+v.y*v.y)+(v.z*v.z+v.w*v.w);
    #pragma unroll
    for (int off = 32; off >= 1; off >>= 1) {
        s1 += __shfl_xor(s1, off);
        s2 += __shfl_xor(s2, off);
    }
    float mean = s1*(1.0f/C_);
    float var  = fmaxf(s2*(1.0f/C_) - mean*mean, 0.0f);
    float rstd = rsqrtf(var + 1e-5f);
    float4 gg = *(const float4*)&g[lane*4];
    float4 bv = *(const float4*)&bb[lane*4];
    bf16x4 r;
    r[0] = (__bf16)((v.x-mean)*rstd*gg.x + bv.x);
    r[1] = (__bf16)((v.y-mean)*rstd*gg.y + bv.y);
    r[2] = (__bf16)((v.z-mean)*rstd*gg.z + bv.z);
    r[3] = (__bf16)((v.w-mean)*rstd*gg.w + bv.w);
    *(bf16x4*)&out[row*C_ + lane*4] = r;
}

// ---------------------------------------------------------------------------
// wprep2: all 8 weight matrices -> bf16 W^T[n][k] in one launch.
// ---------------------------------------------------------------------------
__global__ __launch_bounds__(256) void wprep2(
    const float* __restrict__ Wqkv, const float* __restrict__ Wproj,
    const float* __restrict__ W1,   const float* __restrict__ W2,
    __bf16* __restrict__ wT)
{
    int z = blockIdx.z, which = z >> 1, layer = z & 1;
    const float* src; __bf16* dst; int NC;
    if (which == 0) {
        src = Wqkv + (size_t)layer*C_*768;
        dst = wT   + (size_t)layer*768*256;
        NC  = 768;
    } else {
        NC = 256;
        const float* b3 = (which == 1) ? Wproj : (which == 2) ? W1 : W2;
        src = b3 + (size_t)layer*65536;
        dst = wT + 2*768*256 + (size_t)((which-1)*2 + layer)*65536;
    }
    int n0 = blockIdx.x*32; if (n0 >= NC) return;
    int k0 = blockIdx.y*32;
    __shared__ float tile[32][33];
    int c = threadIdx.x & 31, r = threadIdx.x >> 5;
    for (int rr = r; rr < 32; rr += 8)
        tile[rr][c] = src[(size_t)(k0+rr)*NC + n0 + c];
    __syncthreads();
    for (int rr = r; rr < 32; rr += 8)
        dst[(size_t)(n0+rr)*256 + k0 + c] = (__bf16)tile[c][rr];
}

// ---------------------------------------------------------------------------
// gemm4: double-buffered LDS, one barrier per k-step after the MFMA phase.
// STATS=true (last fc2 only): per-row sum/sumsq of final t via shuffles +
// 2 atomics/row -- feeds featln.
// ---------------------------------------------------------------------------
template<int NC, bool ADD, bool GELU, bool BIAS, bool OUTBF, bool STATS>
__global__ __launch_bounds__(256) void gemm4(
    const __bf16* __restrict__ A, const __bf16* __restrict__ Wt,
    const float* __restrict__ bias, float* __restrict__ outF,
    __bf16* __restrict__ outB, float* __restrict__ stats)
{
    __shared__ __align__(16) __bf16 As[2][64*64];
    __shared__ __align__(16) __bf16 Bs[2][64*64];
    int r0 = blockIdx.x*64, c0 = blockIdx.y*64;
    int tid = threadIdx.x;
    int wv = tid >> 6, lane = tid & 63, quad = lane >> 4, mn = lane & 15;
    int sr = tid >> 2, sc = tid & 3;
    int ga = r0 + sr; if (ga >= M_) ga = M_ - 1;

    f32x4 acc[4];
    #pragma unroll
    for (int ct = 0; ct < 4; ++ct)
        #pragma unroll
        for (int rr = 0; rr < 4; ++rr) acc[ct][rr] = 0.f;

    bf16x8 ra0, ra1, rb0, rb1;
#define GLOAD(KC) do {                                                   \
        ra0 = *(const bf16x8*)&A[(size_t)ga*256 + (KC)*64 + sc*8];       \
        ra1 = *(const bf16x8*)&A[(size_t)ga*256 + (KC)*64 + sc*8 + 32];  \
        rb0 = *(const bf16x8*)&Wt[(size_t)(c0+sr)*256 + (KC)*64 + sc*8]; \
        rb1 = *(const bf16x8*)&Wt[(size_t)(c0+sr)*256 + (KC)*64 + sc*8 + 32]; \
    } while (0)
#define SSTORE(BUF) do {                                                 \
        *(bf16x8*)&As[BUF][sr*64 + ((sc ^ (sr & 7))*8)]       = ra0;     \
        *(bf16x8*)&As[BUF][sr*64 + (((sc+4) ^ (sr & 7))*8)]   = ra1;     \
        *(bf16x8*)&Bs[BUF][sr*64 + ((sc ^ (sr & 7))*8)]       = rb0;     \
        *(bf16x8*)&Bs[BUF][sr*64 + (((sc+4) ^ (sr & 7))*8)]   = rb1;     \
    } while (0)

    GLOAD(0);
    SSTORE(0);
    __syncthreads();

    for (int kc = 0; kc < 4; ++kc) {
        int cur = kc & 1;
        if (kc < 3) GLOAD(kc+1);
        __builtin_amdgcn_sched_barrier(0);   // pin prefetch issue before compute

        #pragma unroll
        for (int h = 0; h < 2; ++h) {
            bf16x8 a = *(const bf16x8*)&As[cur][(wv*16 + mn)*64 + (((h*4+quad) ^ (mn & 7))*8)];
            #pragma unroll
            for (int ct = 0; ct < 4; ++ct) {
                bf16x8 b = *(const bf16x8*)&Bs[cur][(ct*16 + mn)*64 + (((h*4+quad) ^ (mn & 7))*8)];
                acc[ct] = __builtin_amdgcn_mfma_f32_16x16x32_bf16(a, b, acc[ct], 0, 0, 0);
            }
        }

        if (kc < 3) {
            SSTORE(cur^1);     // vmcnt(0) lands here, after the MFMA phase
            __syncthreads();
        }
    }
#undef GLOAD
#undef SSTORE

    float rs1[4] = {0.f,0.f,0.f,0.f}, rs2[4] = {0.f,0.f,0.f,0.f};
    #pragma unroll
    for (int ct = 0; ct < 4; ++ct) {
        int col = c0 + ct*16 + mn;
        #pragma unroll
        for (int rr = 0; rr < 4; ++rr) {
            int row = r0 + wv*16 + quad*4 + rr;
            if (row >= M_) continue;
            float val = acc[ct][rr];
            if (BIAS) val += bias[col];
            if (GELU) val = 0.5f*val*(1.f + erff(val*0.70710678118654752f));
            size_t oi = (size_t)row*NC + col;
            if (OUTBF) outB[oi] = (__bf16)val;
            else if (ADD) {
                float tv = outF[oi] + val;
                outF[oi] = tv;
                if (STATS) { rs1[rr] += tv; rs2[rr] += tv*tv; }
            }
            else outF[oi] = val;
        }
    }
    if (STATS) {
        #pragma unroll
        for (int rr = 0; rr < 4; ++rr) {
            float s1 = rs1[rr], s2 = rs2[rr];
            s1 += __shfl_xor(s1, 1); s1 += __shfl_xor(s1, 2);
            s1 += __shfl_xor(s1, 4); s1 += __shfl_xor(s1, 8);
            s2 += __shfl_xor(s2, 1); s2 += __shfl_xor(s2, 2);
            s2 += __shfl_xor(s2, 4); s2 += __shfl_xor(s2, 8);
            int row = r0 + wv*16 + quad*4 + rr;
            if (mn == 0 && row < M_) {
                atomicAdd(&stats[2*row],     s1);
                atomicAdd(&stats[2*row + 1], s2);
            }
        }
    }
}

// ---------------------------------------------------------------------------
// gemm_qkv4: same pipelined core; epilogue packs qB (scaled by
// log2e/sqrt(hd) so attention can use raw v_exp_f32 = 2^x), kB, vB^T.
// ---------------------------------------------------------------------------
__global__ __launch_bounds__(256) void gemm_qkv4(
    const __bf16* __restrict__ A, const __bf16* __restrict__ Wt,
    __bf16* __restrict__ qB, __bf16* __restrict__ kB, __bf16* __restrict__ vB)
{
    __shared__ __align__(16) __bf16 As[2][64*64];
    __shared__ __align__(16) __bf16 Bs[2][64*64];
    int r0 = blockIdx.x*64, c0 = blockIdx.y*64;
    int tid = threadIdx.x;
    int wv = tid >> 6, lane = tid & 63, quad = lane >> 4, mn = lane & 15;
    int sr = tid >> 2, sc = tid & 3;
    int ga = r0 + sr; if (ga >= M_) ga = M_ - 1;

    f32x4 acc[4];
    #pragma unroll
    for (int ct = 0; ct < 4; ++ct)
        #pragma unroll
        for (int rr = 0; rr < 4; ++rr) acc[ct][rr] = 0.f;

    bf16x8 ra0, ra1, rb0, rb1;
#define GLOAD(KC) do {                                                   \
        ra0 = *(const bf16x8*)&A[(size_t)ga*256 + (KC)*64 + sc*8];       \
        ra1 = *(const bf16x8*)&A[(size_t)ga*256 + (KC)*64 + sc*8 + 32];  \
        rb0 = *(const bf16x8*)&Wt[(size_t)(c0+sr)*256 + (KC)*64 + sc*8]; \
        rb1 = *(const bf16x8*)&Wt[(size_t)(c0+sr)*256 + (KC)*64 + sc*8 + 32]; \
    } while (0)
#define SSTORE(BUF) do {                                                 \
        *(bf16x8*)&As[BUF][sr*64 + ((sc ^ (sr & 7))*8)]       = ra0;     \
        *(bf16x8*)&As[BUF][sr*64 + (((sc+4) ^ (sr & 7))*8)]   = ra1;     \
        *(bf16x8*)&Bs[BUF][sr*64 + ((sc ^ (sr & 7))*8)]       = rb0;     \
        *(bf16x8*)&Bs[BUF][sr*64 + (((sc+4) ^ (sr & 7))*8)]   = rb1;     \
    } while (0)

    GLOAD(0);
    SSTORE(0);
    __syncthreads();

    for (int kc = 0; kc < 4; ++kc) {
        int cur = kc & 1;
        if (kc < 3) GLOAD(kc+1);
        __builtin_amdgcn_sched_barrier(0);

        #pragma unroll
        for (int h = 0; h < 2; ++h) {
            bf16x8 a = *(const bf16x8*)&As[cur][(wv*16 + mn)*64 + (((h*4+quad) ^ (mn & 7))*8)];
            #pragma unroll
            for (int ct = 0; ct < 4; ++ct) {
                bf16x8 b = *(const bf16x8*)&Bs[cur][(ct*16 + mn)*64 + (((h*4+quad) ^ (mn & 7))*8)];
                acc[ct] = __builtin_amdgcn_mfma_f32_16x16x32_bf16(a, b, acc[ct], 0, 0, 0);
            }
        }

        if (kc < 3) {
            SSTORE(cur^1);
            __syncthreads();
        }
    }
#undef GLOAD
#undef SSTORE

    const float scale = 0.2550348727f;   // log2(e)/sqrt(32)
    #pragma unroll
    for (int ct = 0; ct < 4; ++ct) {
        int col = c0 + ct*16 + mn;
        #pragma unroll
        for (int rr = 0; rr < 4; ++rr) {
            int row = r0 + wv*16 + quad*4 + rr;
            if (row >= M_) continue;
            int b = row / N_, n = row - b*N_;
            float val = acc[ct][rr];
            if (col < 256) {
                int h = col >> 5, dd = col & 31;
                qB[((size_t)(b*NH_+h)*NPAD + n)*32 + dd] = (__bf16)(val*scale);
            } else if (col < 512) {
                int h = (col-256) >> 5, dd = col & 31;
                kB[((size_t)(b*NH_+h)*NPAD + n)*32 + dd] = (__bf16)val;
            } else {
                int h = (col-512) >> 5, dd = col & 31;
                vB[((size_t)(b*NH_+h)*32 + dd)*NPAD + n] = (__bf16)val;
            }
        }
    }
}

// ---------------------------------------------------------------------------
// attn16: attn13's inner structure with QBLK=128 (4 waves x 32 q-rows),
// grid (32, 14). Halves K/V staging traffic: each staged 128-key tile now
// serves 128 q-rows instead of 64 (L2 reads 64MB->32MB, LDS writes halved
// per q-row). Hot compute/LDS-read path identical to attn13; staging spread
// over 256 threads (32B each). Same padded LDS strides, same in-register
// softmax, same double-buffer + single barrier per tile.
// ---------------------------------------------------------------------------
#define LKS 40     // lk row stride (bf16): 32 data + 8 pad
#define LVS 136    // lvt row stride (bf16): 128 data + 8 pad

__device__ __forceinline__ float fexp2(float x) {
    float r; asm("v_exp_f32 %0, %1" : "=v"(r) : "v"(x)); return r;
}
__device__ __forceinline__ unsigned cvtpk_bf16(float lo, float hi) {
    unsigned r;
    asm("v_cvt_pk_bf16_f32 %0, %1, %2" : "=v"(r) : "v"(lo), "v"(hi));
    return r;
}

__global__ __launch_bounds__(256) void attn16(
    const __bf16* __restrict__ qB, const __bf16* __restrict__ kB,
    const __bf16* __restrict__ vB, __bf16* __restrict__ o)
{
    int bh = blockIdx.x, b = bh >> 3, h = bh & 7;
    int q0 = blockIdx.y * 128;
    int tid = threadIdx.x;
    int wv = tid >> 6, lane = tid & 63, lo5 = lane & 31, hi = lane >> 5;

    __shared__ __align__(16) __bf16 lk[2][128*LKS];   // 2 x 10240 B
    __shared__ __align__(16) __bf16 lvt[2][32*LVS];   // 2 x  8704 B

    const __bf16* kbase = kB + (size_t)bh*NPAD*32;
    const __bf16* vbase = vB + (size_t)bh*32*NPAD;

    // This wave owns q rows q0 + wv*32 .. +31 (q0+wv*32+lo5 <= 1791 < NPAD).
    const __bf16* qrow = qB + ((size_t)bh*NPAD + q0 + wv*32 + lo5)*32 + hi*8;
    bf16x8 qf0 = *(const bf16x8*)(qrow);        // d = hi*8 .. +7
    bf16x8 qf1 = *(const bf16x8*)(qrow + 16);   // d = 16+hi*8 .. +7

    f32x16 oaccA, oaccB;
    #pragma unroll
    for (int r = 0; r < 16; ++r) { oaccA[r] = 0.f; oaccB[r] = 0.f; }
    float lsum = 0.f;

    // staging indices: K by 2 threads/row (32B each), V^T by 8 threads/row.
    int sr2 = tid >> 1, hc = tid & 1;           // K: row, 16-elem half
    int vr = tid >> 3, vc = tid & 7;            // V: row, 16-elem chunk

    bf16x8 ks0, ks1, vs0, vs1;
#define ATTN_LOAD(T) do {                                              \
        const __bf16* kp_ = kbase + ((size_t)((T)*128 + sr2))*32 + hc*16; \
        ks0 = *(const bf16x8*)(kp_);                                   \
        ks1 = *(const bf16x8*)(kp_ + 8);                               \
        const __bf16* vp_ = vbase + (size_t)vr*NPAD + (T)*128 + vc*16; \
        vs0 = *(const bf16x8*)(vp_);                                   \
        vs1 = *(const bf16x8*)(vp_ + 8);                               \
    } while (0)
#define ATTN_STORE(BUF) do {                                           \
        __bf16* kd = &lk[BUF][sr2*LKS + hc*16];                        \
        *(bf16x8*)(kd)     = ks0;  *(bf16x8*)(kd + 8) = ks1;           \
        __bf16* vd = &lvt[BUF][vr*LVS + vc*16];                        \
        *(bf16x8*)(vd)     = vs0;  *(bf16x8*)(vd + 8) = vs1;           \
    } while (0)

    ATTN_LOAD(0);
    ATTN_STORE(0);
    __syncthreads();

    for (int t = 0; t < 14; ++t) {
        int cur = t & 1;
        if (t < 13) ATTN_LOAD(t+1);
        __builtin_amdgcn_sched_barrier(0);   // pin prefetch issue before compute

        // --- Phase S: all 8 QK^T MFMAs, 4 independent chains ---
        f32x16 s[4];
        __builtin_amdgcn_s_setprio(1);
        #pragma unroll
        for (int kg = 0; kg < 4; ++kg) {
            const __bf16* kf = &lk[cur][(kg*32 + lo5)*LKS + hi*8];
            bf16x8 kf0 = *(const bf16x8*)(kf);
            bf16x8 kf1 = *(const bf16x8*)(kf + 16);
            #pragma unroll
            for (int r = 0; r < 16; ++r) s[kg][r] = 0.f;
            s[kg] = __builtin_amdgcn_mfma_f32_32x32x16_bf16(kf0, qf0, s[kg], 0, 0, 0);
            s[kg] = __builtin_amdgcn_mfma_f32_32x32x16_bf16(kf1, qf1, s[kg], 0, 0, 0);
        }
        __builtin_amdgcn_s_setprio(0);

        // --- Phase E+P per kg: exp2, row-sum, pack, PV MFMA (2 chains) ---
        #pragma unroll
        for (int kg = 0; kg < 4; ++kg) {
            float p[16];
            #pragma unroll
            for (int r = 0; r < 16; ++r) p[r] = fexp2(s[kg][r]);
            float l0 = 0.f, l1 = 0.f;
            #pragma unroll
            for (int r = 0; r < 8; ++r) { l0 += p[r]; l1 += p[r+8]; }
            lsum += l0 + l1;

            unsigned a0 = cvtpk_bf16(p[0],  p[1]),  a1 = cvtpk_bf16(p[2],  p[3]);
            unsigned b0 = cvtpk_bf16(p[4],  p[5]),  b1 = cvtpk_bf16(p[6],  p[7]);
            unsigned c0 = cvtpk_bf16(p[8],  p[9]),  c1 = cvtpk_bf16(p[10], p[11]);
            unsigned d0 = cvtpk_bf16(p[12], p[13]), d1 = cvtpk_bf16(p[14], p[15]);
            asm("v_permlane32_swap_b32 %0, %1" : "+v"(a0), "+v"(b0));
            asm("v_permlane32_swap_b32 %0, %1" : "+v"(a1), "+v"(b1));
            asm("v_permlane32_swap_b32 %0, %1" : "+v"(c0), "+v"(d0));
            asm("v_permlane32_swap_b32 %0, %1" : "+v"(c1), "+v"(d1));
            union { bf16x8 v; unsigned u[4]; } f0, f1;
            f0.u[0] = a0; f0.u[1] = a1; f0.u[2] = b0; f0.u[3] = b1;
            f1.u[0] = c0; f1.u[1] = c1; f1.u[2] = d0; f1.u[3] = d1;

            const __bf16* vf = &lvt[cur][lo5*LVS + kg*32 + hi*8];
            bf16x8 vf0 = *(const bf16x8*)(vf);
            bf16x8 vf1 = *(const bf16x8*)(vf + 16);
            __builtin_amdgcn_s_setprio(1);
            if (kg & 1) {
                oaccB = __builtin_amdgcn_mfma_f32_32x32x16_bf16(f0.v, vf0, oaccB, 0, 0, 0);
                oaccB = __builtin_amdgcn_mfma_f32_32x32x16_bf16(f1.v, vf1, oaccB, 0, 0, 0);
            } else {
                oaccA = __builtin_amdgcn_mfma_f32_32x32x16_bf16(f0.v, vf0, oaccA, 0, 0, 0);
                oaccA = __builtin_amdgcn_mfma_f32_32x32x16_bf16(f1.v, vf1, oaccA, 0, 0, 0);
            }
            __builtin_amdgcn_s_setprio(0);
        }

        if (t < 13) {
            ATTN_STORE(cur^1);    // vmcnt(0) lands here, after the compute
            __syncthreads();
        }
    }
#undef ATTN_LOAD
#undef ATTN_STORE

    // l(q): halves hold disjoint key subsets -> combine; subtract 63 pads.
    lsum += __shfl_xor(lsum, 32);
    float inv = 1.0f / (lsum - 63.0f);       // lane lo5 holds inv for its q

    #pragma unroll
    for (int r = 0; r < 16; ++r) {
        float oa = oaccA[r] + oaccB[r];
        int qrw = (r & 3) + 8*(r >> 2) + 4*hi;
        float li = __shfl(inv, qrw);
        int q = q0 + wv*32 + qrw;
        if (q < N_)
            o[((size_t)b*N_ + q)*C_ + h*HD_ + lo5] = (__bf16)(oa * li);
    }
}

// ---------------------------------------------------------------------------
// featln: fused final-LayerNorm + feature transpose + cls extraction.
// ---------------------------------------------------------------------------
__global__ __launch_bounds__(256) void featln(
    const float* __restrict__ t, const float* __restrict__ stats,
    const float* __restrict__ g, const float* __restrict__ bb,
    float* __restrict__ out_cls, float* __restrict__ out_feat)
{
    int bx = blockIdx.x;
    if (bx == 54) {
        if (blockIdx.y != 0) return;
        int b = blockIdx.z, c = threadIdx.x;
        size_t row = (size_t)b*N_;
        float s1 = stats[2*row], s2 = stats[2*row+1];
        float mean = s1*(1.0f/C_);
        float rstd = rsqrtf(fmaxf(s2*(1.0f/C_) - mean*mean, 0.0f) + 1e-5f);
        out_cls[b*C_ + c] = (t[row*C_ + c] - mean)*rstd*g[c] + bb[c];
        return;
    }
    __shared__ float tl[32][33];
    int p0 = bx*32, c0 = blockIdx.y*32, b = blockIdx.z;
    int cc = threadIdx.x & 31, rr = threadIdx.x >> 5;
    float gg = g[c0+cc], bv = bb[c0+cc];
    for (int i = rr; i < 32; i += 8) {
        size_t row = (size_t)b*N_ + 1 + p0 + i;
        float s1 = stats[2*row], s2 = stats[2*row+1];
        float mean = s1*(1.0f/C_);
        float rstd = rsqrtf(fmaxf(s2*(1.0f/C_) - mean*mean, 0.0f) + 1e-5f);
        tl[i][cc] = (t[row*C_ + c0 + cc] - mean)*rstd*gg + bv;
    }
    __syncthreads();
    for (int i = rr; i < 32; i += 8)
        out_feat[((size_t)(b*C_) + c0 + i)*P_ + p0 + cc] = tl[cc][i];
}

// ---------------------------------------------------------------------------
extern "C" void kernel_launch(void* const* d_in, const int* in_sizes, int n_in,
                              void* d_out, int out_size, void* d_ws, size_t ws_size,
                              hipStream_t stream)
{
    const float* x        = (const float*)d_in[0];
    const float* W_pe     = (const float*)d_in[1];
    const float* b_pe     = (const float*)d_in[2];
    const float* cls_tok  = (const float*)d_in[3];
    const float* ln1_g    = (const float*)d_in[4];
    const float* ln1_b    = (const float*)d_in[5];
    const float* Wqkv     = (const float*)d_in[6];
    const float* Wproj    = (const float*)d_in[7];
    const float* bproj    = (const float*)d_in[8];
    const float* ln2_g    = (const float*)d_in[9];
    const float* ln2_b    = (const float*)d_in[10];
    const float* W1       = (const float*)d_in[11];
    const float* b1       = (const float*)d_in[12];
    const float* W2       = (const float*)d_in[13];
    const float* b2       = (const float*)d_in[14];
    const float* normf_g  = (const float*)d_in[15];
    const float* normf_b  = (const float*)d_in[16];

    const size_t MC = (size_t)M_*C_;    // 1,770,496
    float*  ws  = (float*)d_ws;
    float*  t   = ws;                               // MC fp32
    float*  stats = ws + MC;                        // 2*M_ fp32 (final-LN stats)
    __bf16* ybf = (__bf16*)(ws + 2*MC);             // MC bf16
    __bf16* hbf = (__bf16*)(ws + 2*MC + MC/2);      // MC bf16
    __bf16* obf = (__bf16*)(ws + 2*MC + MC);        // MC bf16
    __bf16* wT  = (__bf16*)(ws + 2*MC + 3*(MC/2));  // 786432 bf16
    __bf16* qB  = wT + 2*768*256 + 6*256*256;       // [32][NPAD][32]
    __bf16* kB  = qB + (size_t)B_*NH_*NPAD*32;
    __bf16* vB  = kB + (size_t)B_*NH_*NPAD*32;      // [32][32][NPAD]

    __bf16* projT = wT + 2*768*256;
    __bf16* w1T   = projT + 2*256*256;
    __bf16* w2T   = w1T   + 2*256*256;

    float* out_cls  = (float*)d_out;
    float* out_feat = out_cls + B_*C_;

    wprep2<<<dim3(24, 8, 8), 256, 0, stream>>>(Wqkv, Wproj, W1, W2, wT);
    embed3<<<NB_EMBED + 252 + 55, 256, 0, stream>>>(
        x, W_pe, b_pe, cls_tok, t, kB, vB, stats);

    const int GRID_M = (M_ + 63) / 64;   // 109
    for (int i = 0; i < 2; ++i) {
        ln4<<<M_/4, 256, 0, stream>>>(t, ybf, ln1_g + i*C_, ln1_b + i*C_);
        gemm_qkv4<<<dim3(GRID_M, 12), 256, 0, stream>>>(
            ybf, wT + (size_t)i*768*256, qB, kB, vB);
        attn16<<<dim3(32, 14), 256, 0, stream>>>(qB, kB, vB, obf);
        gemm4<256,true,false,true,false,false><<<dim3(GRID_M, 4), 256, 0, stream>>>(
            obf, projT + (size_t)i*65536, bproj + i*C_, t, nullptr, nullptr);
        ln4<<<M_/4, 256, 0, stream>>>(t, ybf, ln2_g + i*C_, ln2_b + i*C_);
        gemm4<256,false,true,true,true,false><<<dim3(GRID_M, 4), 256, 0, stream>>>(
            ybf, w1T + (size_t)i*65536, b1 + i*C_, nullptr, hbf, nullptr);
        if (i == 0)
            gemm4<256,true,false,true,false,false><<<dim3(GRID_M, 4), 256, 0, stream>>>(
                hbf, w2T + (size_t)i*65536, b2 + i*C_, t, nullptr, nullptr);
        else
            gemm4<256,true,false,true,false,true><<<dim3(GRID_M, 4), 256, 0, stream>>>(
                hbf, w2T + (size_t)i*65536, b2 + i*C_, t, nullptr, stats);
    }

    featln<<<dim3(55, 8, 4), 256, 0, stream>>>(
        t, stats, normf_g, normf_b, out_cls, out_feat);
}

// Round 9
// 266.429 us; speedup vs baseline: 1.1441x; 1.0418x over previous
//
#include <hip/hip_runtime.h>
#include <hip/hip_bf16.h>
#include <math.h>

#define B_   4
#define CIN  64
#define P_   1728
#define N_   1729
#define C_   256
#define NH_  8
#define HD_  32
#define M_   (B_*N_)   // 6916 rows
#define NPAD 1792      // 28 * 64
#define NB_EMBED 6916  // (B_*N_*C_)/256

typedef __bf16 bf16x8 __attribute__((ext_vector_type(8)));
typedef __bf16 bf16x4 __attribute__((ext_vector_type(4)));
typedef float  f32x4  __attribute__((ext_vector_type(4)));
typedef float  f32x16 __attribute__((ext_vector_type(16)));

// ---------------------------------------------------------------------------
// embed3: patch embed + (extra blocks) kB/vB pad zeroing + stats zeroing.
// ---------------------------------------------------------------------------
__global__ __launch_bounds__(256) void embed3(
    const float* __restrict__ x, const float* __restrict__ Wpe,
    const float* __restrict__ bpe, const float* __restrict__ cls,
    float* __restrict__ t, __bf16* __restrict__ kB, __bf16* __restrict__ vB,
    float* __restrict__ stats)
{
    if (blockIdx.x >= NB_EMBED) {
        int ex = blockIdx.x - NB_EMBED;
        if (ex < 252) {               // padzero: keys n in [N_, NPAD)
            int idx = ex*256 + threadIdx.x;
            if (idx < 32*63*32) {
                int d  = idx & 31;
                int n  = (idx >> 5) % 63 + N_;
                int bh = idx / (63*32);
                kB[((size_t)bh*NPAD + n)*32 + d] = (__bf16)0.f;
                vB[((size_t)bh*32 + d)*NPAD + n] = (__bf16)0.f;
            }
        } else {                      // zero final-LN stats accumulator
            int si = (ex - 252)*256 + threadIdx.x;
            if (si < 2*M_) stats[si] = 0.f;
        }
        return;
    }
    int idx = blockIdx.x*256 + threadIdx.x;        // [0, B*N*C)
    int c   = idx & 255;
    int n   = (idx >> 8) % N_;
    int b   = idx / (N_*256);
    if (n == 0) { t[idx] = cls[c]; return; }
    int p = n - 1;
    float acc = bpe[c];
    for (int ci = 0; ci < CIN; ++ci)
        acc += x[(size_t)(b*CIN + ci)*P_ + p] * Wpe[ci*C_ + c];
    t[idx] = acc;
}

// ---------------------------------------------------------------------------
// ln4: LayerNorm, 4 rows/block (one wave each), float4 in, bf16x4 out.
// Standalone LN measured cheaper than fusing into GEMM (R5: +28us, R7: +22us).
// ---------------------------------------------------------------------------
__global__ __launch_bounds__(256) void ln4(
    const float* __restrict__ in, __bf16* __restrict__ out,
    const float* __restrict__ g, const float* __restrict__ bb)
{
    int wv = threadIdx.x >> 6, lane = threadIdx.x & 63;
    size_t row = (size_t)blockIdx.x*4 + wv;
    float4 v = *(const float4*)&in[row*C_ + lane*4];
    float s1 = (v.x+v.y)+(v.z+v.w);
    float s2 = (v.x*v.x+v.y*v.y)+(v.z*v.z+v.w*v.w);
    #pragma unroll
    for (int off = 32; off >= 1; off >>= 1) {
        s1 += __shfl_xor(s1, off);
        s2 += __shfl_xor(s2, off);
    }
    float mean = s1*(1.0f/C_);
    float var  = fmaxf(s2*(1.0f/C_) - mean*mean, 0.0f);
    float rstd = rsqrtf(var + 1e-5f);
    float4 gg = *(const float4*)&g[lane*4];
    float4 bv = *(const float4*)&bb[lane*4];
    bf16x4 r;
    r[0] = (__bf16)((v.x-mean)*rstd*gg.x + bv.x);
    r[1] = (__bf16)((v.y-mean)*rstd*gg.y + bv.y);
    r[2] = (__bf16)((v.z-mean)*rstd*gg.z + bv.z);
    r[3] = (__bf16)((v.w-mean)*rstd*gg.w + bv.w);
    *(bf16x4*)&out[row*C_ + lane*4] = r;
}

// ---------------------------------------------------------------------------
// wprep2: all 8 weight matrices -> bf16 W^T[n][k] in one launch.
// ---------------------------------------------------------------------------
__global__ __launch_bounds__(256) void wprep2(
    const float* __restrict__ Wqkv, const float* __restrict__ Wproj,
    const float* __restrict__ W1,   const float* __restrict__ W2,
    __bf16* __restrict__ wT)
{
    int z = blockIdx.z, which = z >> 1, layer = z & 1;
    const float* src; __bf16* dst; int NC;
    if (which == 0) {
        src = Wqkv + (size_t)layer*C_*768;
        dst = wT   + (size_t)layer*768*256;
        NC  = 768;
    } else {
        NC = 256;
        const float* b3 = (which == 1) ? Wproj : (which == 2) ? W1 : W2;
        src = b3 + (size_t)layer*65536;
        dst = wT + 2*768*256 + (size_t)((which-1)*2 + layer)*65536;
    }
    int n0 = blockIdx.x*32; if (n0 >= NC) return;
    int k0 = blockIdx.y*32;
    __shared__ float tile[32][33];
    int c = threadIdx.x & 31, r = threadIdx.x >> 5;
    for (int rr = r; rr < 32; rr += 8)
        tile[rr][c] = src[(size_t)(k0+rr)*NC + n0 + c];
    __syncthreads();
    for (int rr = r; rr < 32; rr += 8)
        dst[(size_t)(n0+rr)*256 + k0 + c] = (__bf16)tile[c][rr];
}

// ---------------------------------------------------------------------------
// gemm4: double-buffered LDS, one barrier per k-step after the MFMA phase.
// STATS=true (last fc2 only): per-row sum/sumsq of final t via shuffles +
// 2 atomics/row -- feeds featln.
// ---------------------------------------------------------------------------
template<int NC, bool ADD, bool GELU, bool BIAS, bool OUTBF, bool STATS>
__global__ __launch_bounds__(256) void gemm4(
    const __bf16* __restrict__ A, const __bf16* __restrict__ Wt,
    const float* __restrict__ bias, float* __restrict__ outF,
    __bf16* __restrict__ outB, float* __restrict__ stats)
{
    __shared__ __align__(16) __bf16 As[2][64*64];
    __shared__ __align__(16) __bf16 Bs[2][64*64];
    int r0 = blockIdx.x*64, c0 = blockIdx.y*64;
    int tid = threadIdx.x;
    int wv = tid >> 6, lane = tid & 63, quad = lane >> 4, mn = lane & 15;
    int sr = tid >> 2, sc = tid & 3;
    int ga = r0 + sr; if (ga >= M_) ga = M_ - 1;

    f32x4 acc[4];
    #pragma unroll
    for (int ct = 0; ct < 4; ++ct)
        #pragma unroll
        for (int rr = 0; rr < 4; ++rr) acc[ct][rr] = 0.f;

    bf16x8 ra0, ra1, rb0, rb1;
#define GLOAD(KC) do {                                                   \
        ra0 = *(const bf16x8*)&A[(size_t)ga*256 + (KC)*64 + sc*8];       \
        ra1 = *(const bf16x8*)&A[(size_t)ga*256 + (KC)*64 + sc*8 + 32];  \
        rb0 = *(const bf16x8*)&Wt[(size_t)(c0+sr)*256 + (KC)*64 + sc*8]; \
        rb1 = *(const bf16x8*)&Wt[(size_t)(c0+sr)*256 + (KC)*64 + sc*8 + 32]; \
    } while (0)
#define SSTORE(BUF) do {                                                 \
        *(bf16x8*)&As[BUF][sr*64 + ((sc ^ (sr & 7))*8)]       = ra0;     \
        *(bf16x8*)&As[BUF][sr*64 + (((sc+4) ^ (sr & 7))*8)]   = ra1;     \
        *(bf16x8*)&Bs[BUF][sr*64 + ((sc ^ (sr & 7))*8)]       = rb0;     \
        *(bf16x8*)&Bs[BUF][sr*64 + (((sc+4) ^ (sr & 7))*8)]   = rb1;     \
    } while (0)

    GLOAD(0);
    SSTORE(0);
    __syncthreads();

    for (int kc = 0; kc < 4; ++kc) {
        int cur = kc & 1;
        if (kc < 3) GLOAD(kc+1);
        __builtin_amdgcn_sched_barrier(0);   // pin prefetch issue before compute

        #pragma unroll
        for (int h = 0; h < 2; ++h) {
            bf16x8 a = *(const bf16x8*)&As[cur][(wv*16 + mn)*64 + (((h*4+quad) ^ (mn & 7))*8)];
            #pragma unroll
            for (int ct = 0; ct < 4; ++ct) {
                bf16x8 b = *(const bf16x8*)&Bs[cur][(ct*16 + mn)*64 + (((h*4+quad) ^ (mn & 7))*8)];
                acc[ct] = __builtin_amdgcn_mfma_f32_16x16x32_bf16(a, b, acc[ct], 0, 0, 0);
            }
        }

        if (kc < 3) {
            SSTORE(cur^1);     // vmcnt(0) lands here, after the MFMA phase
            __syncthreads();
        }
    }
#undef GLOAD
#undef SSTORE

    float rs1[4] = {0.f,0.f,0.f,0.f}, rs2[4] = {0.f,0.f,0.f,0.f};
    #pragma unroll
    for (int ct = 0; ct < 4; ++ct) {
        int col = c0 + ct*16 + mn;
        #pragma unroll
        for (int rr = 0; rr < 4; ++rr) {
            int row = r0 + wv*16 + quad*4 + rr;
            if (row >= M_) continue;
            float val = acc[ct][rr];
            if (BIAS) val += bias[col];
            if (GELU) val = 0.5f*val*(1.f + erff(val*0.70710678118654752f));
            size_t oi = (size_t)row*NC + col;
            if (OUTBF) outB[oi] = (__bf16)val;
            else if (ADD) {
                float tv = outF[oi] + val;
                outF[oi] = tv;
                if (STATS) { rs1[rr] += tv; rs2[rr] += tv*tv; }
            }
            else outF[oi] = val;
        }
    }
    if (STATS) {
        #pragma unroll
        for (int rr = 0; rr < 4; ++rr) {
            float s1 = rs1[rr], s2 = rs2[rr];
            s1 += __shfl_xor(s1, 1); s1 += __shfl_xor(s1, 2);
            s1 += __shfl_xor(s1, 4); s1 += __shfl_xor(s1, 8);
            s2 += __shfl_xor(s2, 1); s2 += __shfl_xor(s2, 2);
            s2 += __shfl_xor(s2, 4); s2 += __shfl_xor(s2, 8);
            int row = r0 + wv*16 + quad*4 + rr;
            if (mn == 0 && row < M_) {
                atomicAdd(&stats[2*row],     s1);
                atomicAdd(&stats[2*row + 1], s2);
            }
        }
    }
}

// ---------------------------------------------------------------------------
// gemm_qkv7: pipelined core; epilogue packs qB (scaled by log2e/sqrt(hd)),
// kB directly (those writes are 256B-tile contiguous per quad), and vB via
// an LDS transpose (reusing the staging LDS) so the transposed V store is
// n-contiguous -- the old per-lane dd-major scatter had ~8x write
// amplification (8B useful per 64B sector).
// ---------------------------------------------------------------------------
__global__ __launch_bounds__(256) void gemm_qkv7(
    const __bf16* __restrict__ A, const __bf16* __restrict__ Wt,
    __bf16* __restrict__ qB, __bf16* __restrict__ kB, __bf16* __restrict__ vB)
{
    __shared__ __align__(16) __bf16 ABs[4][64*64];   // A dbuf: 0/1, B dbuf: 2/3
    int r0 = blockIdx.x*64, c0 = blockIdx.y*64;
    int tid = threadIdx.x;
    int wv = tid >> 6, lane = tid & 63, quad = lane >> 4, mn = lane & 15;
    int sr = tid >> 2, sc = tid & 3;
    int ga = r0 + sr; if (ga >= M_) ga = M_ - 1;

    f32x4 acc[4];
    #pragma unroll
    for (int ct = 0; ct < 4; ++ct)
        #pragma unroll
        for (int rr = 0; rr < 4; ++rr) acc[ct][rr] = 0.f;

    bf16x8 ra0, ra1, rb0, rb1;
#define GLOAD(KC) do {                                                   \
        ra0 = *(const bf16x8*)&A[(size_t)ga*256 + (KC)*64 + sc*8];       \
        ra1 = *(const bf16x8*)&A[(size_t)ga*256 + (KC)*64 + sc*8 + 32];  \
        rb0 = *(const bf16x8*)&Wt[(size_t)(c0+sr)*256 + (KC)*64 + sc*8]; \
        rb1 = *(const bf16x8*)&Wt[(size_t)(c0+sr)*256 + (KC)*64 + sc*8 + 32]; \
    } while (0)
#define SSTORE(BUF) do {                                                 \
        *(bf16x8*)&ABs[BUF][sr*64 + ((sc ^ (sr & 7))*8)]       = ra0;    \
        *(bf16x8*)&ABs[BUF][sr*64 + (((sc+4) ^ (sr & 7))*8)]   = ra1;    \
        *(bf16x8*)&ABs[2+(BUF)][sr*64 + ((sc ^ (sr & 7))*8)]     = rb0;  \
        *(bf16x8*)&ABs[2+(BUF)][sr*64 + (((sc+4) ^ (sr & 7))*8)] = rb1;  \
    } while (0)

    GLOAD(0);
    SSTORE(0);
    __syncthreads();

    for (int kc = 0; kc < 4; ++kc) {
        int cur = kc & 1;
        if (kc < 3) GLOAD(kc+1);
        __builtin_amdgcn_sched_barrier(0);

        #pragma unroll
        for (int h = 0; h < 2; ++h) {
            bf16x8 a = *(const bf16x8*)&ABs[cur][(wv*16 + mn)*64 + (((h*4+quad) ^ (mn & 7))*8)];
            #pragma unroll
            for (int ct = 0; ct < 4; ++ct) {
                bf16x8 b = *(const bf16x8*)&ABs[2+cur][(ct*16 + mn)*64 + (((h*4+quad) ^ (mn & 7))*8)];
                acc[ct] = __builtin_amdgcn_mfma_f32_16x16x32_bf16(a, b, acc[ct], 0, 0, 0);
            }
        }

        if (kc < 3) {
            SSTORE(cur^1);
            __syncthreads();
        }
    }
#undef GLOAD
#undef SSTORE

    const float scale = 0.2550348727f;   // log2(e)/sqrt(32)
    if (c0 < 512) {
        // q and k: per-quad writes cover a contiguous 4n x 32dd = 256B tile.
        #pragma unroll
        for (int ct = 0; ct < 4; ++ct) {
            int col = c0 + ct*16 + mn;
            #pragma unroll
            for (int rr = 0; rr < 4; ++rr) {
                int row = r0 + wv*16 + quad*4 + rr;
                if (row >= M_) continue;
                int b = row / N_, n = row - b*N_;
                float val = acc[ct][rr];
                if (col < 256) {
                    int h = col >> 5, dd = col & 31;
                    qB[((size_t)(b*NH_+h)*NPAD + n)*32 + dd] = (__bf16)(val*scale);
                } else {
                    int h = (col-256) >> 5, dd = col & 31;
                    kB[((size_t)(b*NH_+h)*NPAD + n)*32 + dd] = (__bf16)val;
                }
            }
        }
    } else {
        // v: LDS transpose (reuse ABs: 64x68 f32 = 17408B <= 32KB) so vB
        // stores are n-contiguous (each thread writes 16 consecutive bf16).
        __syncthreads();                     // all MFMA LDS reads done
        float* vt = (float*)ABs;
        #pragma unroll
        for (int ct = 0; ct < 4; ++ct) {
            int lc = ct*16 + mn;
            #pragma unroll
            for (int rr = 0; rr < 4; ++rr)
                vt[lc*68 + wv*16 + quad*4 + rr] = acc[ct][rr];
        }
        __syncthreads();
        int lc = tid >> 2, nc = (tid & 3)*16;
        int colg = c0 + lc;
        int h = (colg - 512) >> 5, dd = colg & 31;
        #pragma unroll
        for (int j = 0; j < 16; ++j) {
            int row = r0 + nc + j;
            if (row >= M_) continue;
            int b = row / N_, n = row - b*N_;
            vB[((size_t)((b*NH_+h)*32 + dd))*NPAD + n] = (__bf16)vt[lc*68 + nc + j];
        }
    }
}

// ---------------------------------------------------------------------------
// attn17: attn16 structure with QBLK=256 (8 waves x 32 q-rows), grid (32,7).
// Halves K/V staging traffic again (each staged 128-key tile now serves 256
// q-rows). Staging = one 16B load+store per thread. Hot compute/LDS-read
// path identical to attn13/16. lsum -63 pad correction unchanged (every
// wave still sees all 14 key tiles).
// ---------------------------------------------------------------------------
#define LKS 40     // lk row stride (bf16): 32 data + 8 pad
#define LVS 136    // lvt row stride (bf16): 128 data + 8 pad

__device__ __forceinline__ float fexp2(float x) {
    float r; asm("v_exp_f32 %0, %1" : "=v"(r) : "v"(x)); return r;
}
__device__ __forceinline__ unsigned cvtpk_bf16(float lo, float hi) {
    unsigned r;
    asm("v_cvt_pk_bf16_f32 %0, %1, %2" : "=v"(r) : "v"(lo), "v"(hi));
    return r;
}

__global__ __launch_bounds__(512) void attn17(
    const __bf16* __restrict__ qB, const __bf16* __restrict__ kB,
    const __bf16* __restrict__ vB, __bf16* __restrict__ o)
{
    int bh = blockIdx.x, b = bh >> 3, h = bh & 7;
    int q0 = blockIdx.y * 256;
    int tid = threadIdx.x;
    int wv = tid >> 6, lane = tid & 63, lo5 = lane & 31, hi = lane >> 5;

    __shared__ __align__(16) __bf16 lk[2][128*LKS];   // 2 x 10240 B
    __shared__ __align__(16) __bf16 lvt[2][32*LVS];   // 2 x  8704 B

    const __bf16* kbase = kB + (size_t)bh*NPAD*32;
    const __bf16* vbase = vB + (size_t)bh*32*NPAD;

    // This wave owns q rows q0 + wv*32 .. +31 (max 1791 < NPAD).
    const __bf16* qrow = qB + ((size_t)bh*NPAD + q0 + wv*32 + lo5)*32 + hi*8;
    bf16x8 qf0 = *(const bf16x8*)(qrow);        // d = hi*8 .. +7
    bf16x8 qf1 = *(const bf16x8*)(qrow + 16);   // d = 16+hi*8 .. +7

    f32x16 oaccA, oaccB;
    #pragma unroll
    for (int r = 0; r < 16; ++r) { oaccA[r] = 0.f; oaccB[r] = 0.f; }
    float lsum = 0.f;

    // staging: K by 4 threads/row (16B each), V^T by 16 threads/row.
    int ksr = tid >> 2, ksc = tid & 3;          // K: row 0..127, 16B chunk
    int vr  = tid >> 4, vc  = tid & 15;         // V: row 0..31, 16B chunk

    bf16x8 ks0, vs0;
#define ATTN_LOAD(T) do {                                              \
        ks0 = *(const bf16x8*)(kbase + ((size_t)((T)*128 + ksr))*32 + ksc*8); \
        vs0 = *(const bf16x8*)(vbase + (size_t)vr*NPAD + (T)*128 + vc*8);     \
    } while (0)
#define ATTN_STORE(BUF) do {                                           \
        *(bf16x8*)&lk[BUF][ksr*LKS + ksc*8] = ks0;                     \
        *(bf16x8*)&lvt[BUF][vr*LVS + vc*8]  = vs0;                     \
    } while (0)

    ATTN_LOAD(0);
    ATTN_STORE(0);
    __syncthreads();

    for (int t = 0; t < 14; ++t) {
        int cur = t & 1;
        if (t < 13) ATTN_LOAD(t+1);
        __builtin_amdgcn_sched_barrier(0);   // pin prefetch issue before compute

        // --- Phase S: all 8 QK^T MFMAs, 4 independent chains ---
        f32x16 s[4];
        __builtin_amdgcn_s_setprio(1);
        #pragma unroll
        for (int kg = 0; kg < 4; ++kg) {
            const __bf16* kf = &lk[cur][(kg*32 + lo5)*LKS + hi*8];
            bf16x8 kf0 = *(const bf16x8*)(kf);
            bf16x8 kf1 = *(const bf16x8*)(kf + 16);
            #pragma unroll
            for (int r = 0; r < 16; ++r) s[kg][r] = 0.f;
            s[kg] = __builtin_amdgcn_mfma_f32_32x32x16_bf16(kf0, qf0, s[kg], 0, 0, 0);
            s[kg] = __builtin_amdgcn_mfma_f32_32x32x16_bf16(kf1, qf1, s[kg], 0, 0, 0);
        }
        __builtin_amdgcn_s_setprio(0);

        // --- Phase E+P per kg: exp2, row-sum, pack, PV MFMA (2 chains) ---
        #pragma unroll
        for (int kg = 0; kg < 4; ++kg) {
            float p[16];
            #pragma unroll
            for (int r = 0; r < 16; ++r) p[r] = fexp2(s[kg][r]);
            float l0 = 0.f, l1 = 0.f;
            #pragma unroll
            for (int r = 0; r < 8; ++r) { l0 += p[r]; l1 += p[r+8]; }
            lsum += l0 + l1;

            unsigned a0 = cvtpk_bf16(p[0],  p[1]),  a1 = cvtpk_bf16(p[2],  p[3]);
            unsigned b0 = cvtpk_bf16(p[4],  p[5]),  b1 = cvtpk_bf16(p[6],  p[7]);
            unsigned c0 = cvtpk_bf16(p[8],  p[9]),  c1 = cvtpk_bf16(p[10], p[11]);
            unsigned d0 = cvtpk_bf16(p[12], p[13]), d1 = cvtpk_bf16(p[14], p[15]);
            asm("v_permlane32_swap_b32 %0, %1" : "+v"(a0), "+v"(b0));
            asm("v_permlane32_swap_b32 %0, %1" : "+v"(a1), "+v"(b1));
            asm("v_permlane32_swap_b32 %0, %1" : "+v"(c0), "+v"(d0));
            asm("v_permlane32_swap_b32 %0, %1" : "+v"(c1), "+v"(d1));
            union { bf16x8 v; unsigned u[4]; } f0, f1;
            f0.u[0] = a0; f0.u[1] = a1; f0.u[2] = b0; f0.u[3] = b1;
            f1.u[0] = c0; f1.u[1] = c1; f1.u[2] = d0; f1.u[3] = d1;

            const __bf16* vf = &lvt[cur][lo5*LVS + kg*32 + hi*8];
            bf16x8 vf0 = *(const bf16x8*)(vf);
            bf16x8 vf1 = *(const bf16x8*)(vf + 16);
            __builtin_amdgcn_s_setprio(1);
            if (kg & 1) {
                oaccB = __builtin_amdgcn_mfma_f32_32x32x16_bf16(f0.v, vf0, oaccB, 0, 0, 0);
                oaccB = __builtin_amdgcn_mfma_f32_32x32x16_bf16(f1.v, vf1, oaccB, 0, 0, 0);
            } else {
                oaccA = __builtin_amdgcn_mfma_f32_32x32x16_bf16(f0.v, vf0, oaccA, 0, 0, 0);
                oaccA = __builtin_amdgcn_mfma_f32_32x32x16_bf16(f1.v, vf1, oaccA, 0, 0, 0);
            }
            __builtin_amdgcn_s_setprio(0);
        }

        if (t < 13) {
            ATTN_STORE(cur^1);    // vmcnt(0) lands here, after the compute
            __syncthreads();
        }
    }
#undef ATTN_LOAD
#undef ATTN_STORE

    // l(q): halves hold disjoint key subsets -> combine; subtract 63 pads.
    lsum += __shfl_xor(lsum, 32);
    float inv = 1.0f / (lsum - 63.0f);       // lane lo5 holds inv for its q

    #pragma unroll
    for (int r = 0; r < 16; ++r) {
        float oa = oaccA[r] + oaccB[r];
        int qrw = (r & 3) + 8*(r >> 2) + 4*hi;
        float li = __shfl(inv, qrw);
        int q = q0 + wv*32 + qrw;
        if (q < N_)
            o[((size_t)b*N_ + q)*C_ + h*HD_ + lo5] = (__bf16)(oa * li);
    }
}

// ---------------------------------------------------------------------------
// featln: fused final-LayerNorm + feature transpose + cls extraction.
// ---------------------------------------------------------------------------
__global__ __launch_bounds__(256) void featln(
    const float* __restrict__ t, const float* __restrict__ stats,
    const float* __restrict__ g, const float* __restrict__ bb,
    float* __restrict__ out_cls, float* __restrict__ out_feat)
{
    int bx = blockIdx.x;
    if (bx == 54) {
        if (blockIdx.y != 0) return;
        int b = blockIdx.z, c = threadIdx.x;
        size_t row = (size_t)b*N_;
        float s1 = stats[2*row], s2 = stats[2*row+1];
        float mean = s1*(1.0f/C_);
        float rstd = rsqrtf(fmaxf(s2*(1.0f/C_) - mean*mean, 0.0f) + 1e-5f);
        out_cls[b*C_ + c] = (t[row*C_ + c] - mean)*rstd*g[c] + bb[c];
        return;
    }
    __shared__ float tl[32][33];
    int p0 = bx*32, c0 = blockIdx.y*32, b = blockIdx.z;
    int cc = threadIdx.x & 31, rr = threadIdx.x >> 5;
    float gg = g[c0+cc], bv = bb[c0+cc];
    for (int i = rr; i < 32; i += 8) {
        size_t row = (size_t)b*N_ + 1 + p0 + i;
        float s1 = stats[2*row], s2 = stats[2*row+1];
        float mean = s1*(1.0f/C_);
        float rstd = rsqrtf(fmaxf(s2*(1.0f/C_) - mean*mean, 0.0f) + 1e-5f);
        tl[i][cc] = (t[row*C_ + c0 + cc] - mean)*rstd*gg + bv;
    }
    __syncthreads();
    for (int i = rr; i < 32; i += 8)
        out_feat[((size_t)(b*C_) + c0 + i)*P_ + p0 + cc] = tl[cc][i];
}

// ---------------------------------------------------------------------------
extern "C" void kernel_launch(void* const* d_in, const int* in_sizes, int n_in,
                              void* d_out, int out_size, void* d_ws, size_t ws_size,
                              hipStream_t stream)
{
    const float* x        = (const float*)d_in[0];
    const float* W_pe     = (const float*)d_in[1];
    const float* b_pe     = (const float*)d_in[2];
    const float* cls_tok  = (const float*)d_in[3];
    const float* ln1_g    = (const float*)d_in[4];
    const float* ln1_b    = (const float*)d_in[5];
    const float* Wqkv     = (const float*)d_in[6];
    const float* Wproj    = (const float*)d_in[7];
    const float* bproj    = (const float*)d_in[8];
    const float* ln2_g    = (const float*)d_in[9];
    const float* ln2_b    = (const float*)d_in[10];
    const float* W1       = (const float*)d_in[11];
    const float* b1       = (const float*)d_in[12];
    const float* W2       = (const float*)d_in[13];
    const float* b2       = (const float*)d_in[14];
    const float* normf_g  = (const float*)d_in[15];
    const float* normf_b  = (const float*)d_in[16];

    const size_t MC = (size_t)M_*C_;    // 1,770,496
    float*  ws  = (float*)d_ws;
    float*  t   = ws;                               // MC fp32
    float*  stats = ws + MC;                        // 2*M_ fp32 (final-LN stats)
    __bf16* ybf = (__bf16*)(ws + 2*MC);             // MC bf16
    __bf16* hbf = (__bf16*)(ws + 2*MC + MC/2);      // MC bf16
    __bf16* obf = (__bf16*)(ws + 2*MC + MC);        // MC bf16
    __bf16* wT  = (__bf16*)(ws + 2*MC + 3*(MC/2));  // 786432 bf16
    __bf16* qB  = wT + 2*768*256 + 6*256*256;       // [32][NPAD][32]
    __bf16* kB  = qB + (size_t)B_*NH_*NPAD*32;
    __bf16* vB  = kB + (size_t)B_*NH_*NPAD*32;      // [32][32][NPAD]

    __bf16* projT = wT + 2*768*256;
    __bf16* w1T   = projT + 2*256*256;
    __bf16* w2T   = w1T   + 2*256*256;

    float* out_cls  = (float*)d_out;
    float* out_feat = out_cls + B_*C_;

    wprep2<<<dim3(24, 8, 8), 256, 0, stream>>>(Wqkv, Wproj, W1, W2, wT);
    embed3<<<NB_EMBED + 252 + 55, 256, 0, stream>>>(
        x, W_pe, b_pe, cls_tok, t, kB, vB, stats);

    const int GRID_M = (M_ + 63) / 64;   // 109
    for (int i = 0; i < 2; ++i) {
        ln4<<<M_/4, 256, 0, stream>>>(t, ybf, ln1_g + i*C_, ln1_b + i*C_);
        gemm_qkv7<<<dim3(GRID_M, 12), 256, 0, stream>>>(
            ybf, wT + (size_t)i*768*256, qB, kB, vB);
        attn17<<<dim3(32, 7), 512, 0, stream>>>(qB, kB, vB, obf);
        gemm4<256,true,false,true,false,false><<<dim3(GRID_M, 4), 256, 0, stream>>>(
            obf, projT + (size_t)i*65536, bproj + i*C_, t, nullptr, nullptr);
        ln4<<<M_/4, 256, 0, stream>>>(t, ybf, ln2_g + i*C_, ln2_b + i*C_);
        gemm4<256,false,true,true,true,false><<<dim3(GRID_M, 4), 256, 0, stream>>>(
            ybf, w1T + (size_t)i*65536, b1 + i*C_, nullptr, hbf, nullptr);
        if (i == 0)
            gemm4<256,true,false,true,false,false><<<dim3(GRID_M, 4), 256, 0, stream>>>(
                hbf, w2T + (size_t)i*65536, b2 + i*C_, t, nullptr, nullptr);
        else
            gemm4<256,true,false,true,false,true><<<dim3(GRID_M, 4), 256, 0, stream>>>(
                hbf, w2T + (size_t)i*65536, b2 + i*C_, t, nullptr, stats);
    }

    featln<<<dim3(55, 8, 4), 256, 0, stream>>>(
        t, stats, normf_g, normf_b, out_cls, out_feat);
}